// Round 1
// baseline (424.120 us; speedup 1.0000x reference)
//
#include <hip/hip_runtime.h>

// SDPAttention (bug-faithful: output = masked_scores @ v, NOT softmax @ v)
// B=4 H=16 S=1024 DK=64, fp32 in/out.
// Strategy: bf16 MFMA for both matmuls; scores staged in LDS as bf16;
// attn_weight (256 MB) written coalesced -> HBM-write-bound (~51 us floor).
// d_ws layout: [0,8MB) Kb = bf16(K) same layout; [8MB,16MB) Vt = bf16(V^T) [bh][d][s].

typedef __attribute__((ext_vector_type(4))) float floatx4;
typedef __attribute__((ext_vector_type(8))) short shortx8;
typedef __attribute__((ext_vector_type(4))) unsigned short ushortx4;
typedef __attribute__((ext_vector_type(8))) unsigned short ushortx8;
typedef __attribute__((ext_vector_type(4))) int intx4;

#define S_ 1024
#define D_ 64
#define NELEM_ 4194304      // B*H*S*DK
#define ATTN_OFF 4194304    // output elements before attn_weight
#define SCN 1040            // LDS score row stride (ushorts); 1040*2=2080B = 16B-aligned rows

__device__ __forceinline__ unsigned short f32_to_bf16(float f) {
    union { float f; unsigned u; } a; a.f = f;
    unsigned u = a.u;
    u += 0x7fffu + ((u >> 16) & 1u);   // round-to-nearest-even
    return (unsigned short)(u >> 16);
}

__device__ __forceinline__ float bf16_to_f32(unsigned short h) {
    union { unsigned u; float f; } a; a.u = ((unsigned)h) << 16;
    return a.f;
}

__device__ __forceinline__ shortx8 pack8(floatx4 a, floatx4 b) {
    shortx8 r;
    r[0] = (short)f32_to_bf16(a[0]); r[1] = (short)f32_to_bf16(a[1]);
    r[2] = (short)f32_to_bf16(a[2]); r[3] = (short)f32_to_bf16(a[3]);
    r[4] = (short)f32_to_bf16(b[0]); r[5] = (short)f32_to_bf16(b[1]);
    r[6] = (short)f32_to_bf16(b[2]); r[7] = (short)f32_to_bf16(b[3]);
    return r;
}

// ---- pre-kernel: K fp32 -> bf16, same [bh][s][d] layout ----
__global__ __launch_bounds__(256) void cvt_k(const float* __restrict__ in,
                                             unsigned short* __restrict__ out) {
    int i = blockIdx.x * 256 + threadIdx.x;    // one float4 each; grid covers exactly
    floatx4 f = ((const floatx4*)in)[i];
    ushortx4 h;
    h[0] = f32_to_bf16(f[0]); h[1] = f32_to_bf16(f[1]);
    h[2] = f32_to_bf16(f[2]); h[3] = f32_to_bf16(f[3]);
    ((ushortx4*)out)[i] = h;
}

// ---- pre-kernel: V fp32 [bh][s][d] -> bf16 V^T [bh][d][s] ----
__global__ __launch_bounds__(256) void cvt_vt(const float* __restrict__ v,
                                              unsigned short* __restrict__ vt) {
    __shared__ float tile[64][65];   // stride 65: scalar LDS r/w are 2-way max (free)
    int bh = blockIdx.x >> 4;
    int s0 = (blockIdx.x & 15) << 6;
    int tid = threadIdx.x;
    int r  = tid >> 2;
    int c0 = (tid & 3) << 4;
    const float* src = v + ((size_t)(bh * S_ + s0 + r)) * D_ + c0;
    #pragma unroll
    for (int j = 0; j < 4; ++j) {
        floatx4 f = *(const floatx4*)(src + j * 4);
        tile[r][c0 + j*4 + 0] = f[0];
        tile[r][c0 + j*4 + 1] = f[1];
        tile[r][c0 + j*4 + 2] = f[2];
        tile[r][c0 + j*4 + 3] = f[3];
    }
    __syncthreads();
    int d  = tid >> 2;
    int so = (tid & 3) << 4;
    ushortx8 h0, h1;
    #pragma unroll
    for (int j = 0; j < 8; ++j) h0[j] = f32_to_bf16(tile[so + j][d]);
    #pragma unroll
    for (int j = 0; j < 8; ++j) h1[j] = f32_to_bf16(tile[so + 8 + j][d]);
    unsigned short* dst = vt + ((size_t)(bh * D_ + d)) * S_ + s0 + so;
    *(ushortx8*)(dst)     = h0;
    *(ushortx8*)(dst + 8) = h1;
}

// ---- main: per-block = (bh, 16-row q tile); 4 waves ----
__global__ __launch_bounds__(256, 4) void attn_main(
    const float* __restrict__ q,
    const int* __restrict__ mask,
    const unsigned short* __restrict__ Kb,
    const unsigned short* __restrict__ Vt,
    float* __restrict__ out)
{
    __shared__ unsigned short sc[16 * SCN];   // masked scaled scores, bf16
    __shared__ int msk[1024];

    int blk = blockIdx.x;
    int bh = blk >> 6;
    int q0 = (blk & 63) << 4;
    int b  = bh >> 4;
    int tid = threadIdx.x;

    // stage mask row for this batch
    ((intx4*)msk)[tid] = ((const intx4*)(mask + (b << 10)))[tid];

    int w    = tid >> 6;
    int lane = tid & 63;
    int l15  = lane & 15;
    int quad = lane >> 4;

    // Q fragments (A-operand: m=lane&15 (q row), k=quad*8+j (d)); reused all K tiles
    shortx8 qf0, qf1;
    {
        const float* qb = q + ((size_t)(bh * S_ + q0 + l15)) * D_ + quad * 8;
        floatx4 a0 = *(const floatx4*)(qb);
        floatx4 a1 = *(const floatx4*)(qb + 4);
        floatx4 b0 = *(const floatx4*)(qb + 32);
        floatx4 b1 = *(const floatx4*)(qb + 36);
        qf0 = pack8(a0, a1);
        qf1 = pack8(b0, b1);
    }

    __syncthreads();

    // ---- Phase 1: S = scale*QK^T, masked, -> LDS bf16 ----
    {
        const unsigned short* kb = Kb + (size_t)bh * (S_ * D_) + l15 * D_ + quad * 8;
        for (int kt = w; kt < 64; kt += 4) {
            int n0 = kt << 4;
            const unsigned short* kr = kb + n0 * D_;
            shortx8 kf0 = *(const shortx8*)(kr);        // d = quad*8 + 0..7
            shortx8 kf1 = *(const shortx8*)(kr + 32);   // d = 32 + quad*8 + 0..7
            floatx4 acc = {0.f, 0.f, 0.f, 0.f};
            acc = __builtin_amdgcn_mfma_f32_16x16x32_bf16(qf0, kf0, acc, 0, 0, 0);
            acc = __builtin_amdgcn_mfma_f32_16x16x32_bf16(qf1, kf1, acc, 0, 0, 0);
            int mv = msk[n0 + l15];
            int col = n0 + l15;
            #pragma unroll
            for (int r = 0; r < 4; ++r) {
                // C/D: row(q) = quad*4+r, col(key) = lane&15
                unsigned short h = mv ? f32_to_bf16(acc[r] * 0.125f)
                                      : (unsigned short)0xC61C;  // bf16(-10000) = -9984
                sc[(quad * 4 + r) * SCN + col] = h;
            }
        }
    }
    __syncthreads();

    // ---- Phase 2: row softmax -> attn_weight (fp32, coalesced) ----
    {
        float* attnb = out + ATTN_OFF + ((size_t)(bh * S_ + q0)) * S_;
        for (int rr = 0; rr < 4; ++rr) {
            int row = (w << 2) + rr;
            const unsigned short* srow = sc + row * SCN;
            float vv[16];
            #pragma unroll
            for (int c = 0; c < 2; ++c) {
                ushortx8 h = *(const ushortx8*)(srow + (c << 9) + lane * 8);
                #pragma unroll
                for (int j = 0; j < 8; ++j) vv[c * 8 + j] = bf16_to_f32(h[j]);
            }
            float m = vv[0];
            #pragma unroll
            for (int j = 1; j < 16; ++j) m = fmaxf(m, vv[j]);
            #pragma unroll
            for (int off = 32; off; off >>= 1) m = fmaxf(m, __shfl_xor(m, off));
            float s = 0.f;
            #pragma unroll
            for (int j = 0; j < 16; ++j) { vv[j] = __expf(vv[j] - m); s += vv[j]; }
            #pragma unroll
            for (int off = 32; off; off >>= 1) s += __shfl_xor(s, off);
            float inv = 1.0f / s;
            float* arow = attnb + (size_t)row * S_ + lane * 8;
            #pragma unroll
            for (int c = 0; c < 2; ++c) {
                floatx4 o0 = { vv[c*8+0]*inv, vv[c*8+1]*inv, vv[c*8+2]*inv, vv[c*8+3]*inv };
                floatx4 o1 = { vv[c*8+4]*inv, vv[c*8+5]*inv, vv[c*8+6]*inv, vv[c*8+7]*inv };
                *(floatx4*)(arow + (c << 9))     = o0;
                *(floatx4*)(arow + (c << 9) + 4) = o1;
            }
        }
    }

    // ---- Phase 3: O = S_masked @ V (bug-faithful) ----
    {
        int d0 = w << 4;   // each wave owns 16 d-columns
        const unsigned short* vtr = Vt + ((size_t)(bh * D_ + d0 + l15)) * S_ + quad * 8;
        const unsigned short* sr  = sc + l15 * SCN + quad * 8;
        floatx4 oacc = {0.f, 0.f, 0.f, 0.f};
        #pragma unroll 4
        for (int ks = 0; ks < 32; ++ks) {
            shortx8 af = *(const shortx8*)(sr  + (ks << 5));  // A: m=q row, k=key
            shortx8 bf = *(const shortx8*)(vtr + (ks << 5));  // B: n=d col, k=key
            oacc = __builtin_amdgcn_mfma_f32_16x16x32_bf16(af, bf, oacc, 0, 0, 0);
        }
        float* ob = out + ((size_t)(bh * S_ + q0 + (quad << 2))) * D_ + d0 + l15;
        #pragma unroll
        for (int r = 0; r < 4; ++r) ob[(size_t)r * D_] = oacc[r];
    }
}

extern "C" void kernel_launch(void* const* d_in, const int* in_sizes, int n_in,
                              void* d_out, int out_size, void* d_ws, size_t ws_size,
                              hipStream_t stream) {
    const float* q   = (const float*)d_in[0];
    const float* k   = (const float*)d_in[1];
    const float* v   = (const float*)d_in[2];
    const int* mask  = (const int*)d_in[3];
    float* out = (float*)d_out;
    unsigned short* Kb = (unsigned short*)d_ws;       // 8 MB
    unsigned short* Vt = Kb + NELEM_;                 // 8 MB
    cvt_k  <<<4096, 256, 0, stream>>>(k, Kb);
    cvt_vt <<<1024, 256, 0, stream>>>(v, Vt);
    attn_main<<<4096, 256, 0, stream>>>(q, mask, Kb, Vt, out);
}

// Round 2
// 380.007 us; speedup vs baseline: 1.1161x; 1.1161x over previous
//
#include <hip/hip_runtime.h>

// SDPAttention (bug-faithful: output = masked_scores @ v, NOT softmax @ v)
// B=4 H=16 S=1024 DK=64, fp32 in/out.
// R2: fragment-major repack of K and V in d_ws so the main kernel's global
// loads are fully coalesced (R1 had 128B/2048B lane-stride gathers -> ~4x L2
// traffic amplification, est. ~120us hidden cost).
// d_ws: [0,8MB) KbT[bh][kt][lane][16]  (lane = quad*16+l15; [0..7]=d quad*8.., [8..15]=d 32+quad*8..)
//       [8MB,16MB) VtP[bh][dt][ks][lane][8] (bf16 V fragment for PV mfma step ks)

typedef __attribute__((ext_vector_type(4))) float floatx4;
typedef __attribute__((ext_vector_type(8))) short shortx8;
typedef __attribute__((ext_vector_type(8))) unsigned short ushortx8;
typedef __attribute__((ext_vector_type(4))) int intx4;

#define S_ 1024
#define D_ 64
#define NELEM_ 4194304      // B*H*S*DK
#define ATTN_OFF 4194304    // output elements before attn_weight
#define SCN 1040            // LDS score row stride (ushorts); 2080B rows, 16B aligned

__device__ __forceinline__ unsigned short f32_to_bf16(float f) {
    union { float f; unsigned u; } a; a.f = f;
    unsigned u = a.u;
    u += 0x7fffu + ((u >> 16) & 1u);   // round-to-nearest-even
    return (unsigned short)(u >> 16);
}

__device__ __forceinline__ float bf16_to_f32(unsigned short h) {
    union { unsigned u; float f; } a; a.u = ((unsigned)h) << 16;
    return a.f;
}

__device__ __forceinline__ ushortx8 pack8u(floatx4 a, floatx4 b) {
    ushortx8 r;
    r[0] = f32_to_bf16(a[0]); r[1] = f32_to_bf16(a[1]);
    r[2] = f32_to_bf16(a[2]); r[3] = f32_to_bf16(a[3]);
    r[4] = f32_to_bf16(b[0]); r[5] = f32_to_bf16(b[1]);
    r[6] = f32_to_bf16(b[2]); r[7] = f32_to_bf16(b[3]);
    return r;
}

// ---- pre-kernel: K fp32 [bh][s][d] -> KbT fragment-major bf16 ----
// one thread per (bh, kt, lane): writes that lane's 16-ushort (32B) fragment pair.
__global__ __launch_bounds__(256) void kpack(const float* __restrict__ k,
                                             unsigned short* __restrict__ kbt) {
    int g = blockIdx.x * 256 + threadIdx.x;   // 262144 total
    int lane = g & 63;
    int kt   = (g >> 6) & 63;
    int bh   = g >> 12;
    int quad = lane >> 4;
    int l15  = lane & 15;
    const float* src = k + ((size_t)(bh * S_ + kt * 16 + l15)) * D_ + quad * 8;
    floatx4 f0 = *(const floatx4*)(src);
    floatx4 f1 = *(const floatx4*)(src + 4);
    floatx4 f2 = *(const floatx4*)(src + 32);
    floatx4 f3 = *(const floatx4*)(src + 36);
    unsigned short* dst = kbt + (size_t)g * 16;
    *(ushortx8*)(dst)     = pack8u(f0, f1);
    *(ushortx8*)(dst + 8) = pack8u(f2, f3);
}

// ---- pre-kernel: V fp32 [bh][s][d] -> VtP fragment-major bf16 ----
// LDS-transpose 64x64 tiles, emit PV B-fragments: VtP[bh][dt][ks][lane][8],
// fragment value = V[bh][ks*32 + quad*8 + j][dt*16 + l15].
__global__ __launch_bounds__(256) void vpack(const float* __restrict__ v,
                                             unsigned short* __restrict__ vtp) {
    __shared__ float tile[64][65];
    int bh = blockIdx.x >> 4;
    int s0 = (blockIdx.x & 15) << 6;
    int tid = threadIdx.x;
    int r  = tid >> 2;
    int c0 = (tid & 3) << 4;
    const float* src = v + ((size_t)(bh * S_ + s0 + r)) * D_ + c0;
    #pragma unroll
    for (int j = 0; j < 4; ++j) {
        floatx4 f = *(const floatx4*)(src + j * 4);
        tile[r][c0 + j*4 + 0] = f[0];
        tile[r][c0 + j*4 + 1] = f[1];
        tile[r][c0 + j*4 + 2] = f[2];
        tile[r][c0 + j*4 + 3] = f[3];
    }
    __syncthreads();
    int d  = tid >> 2;          // 0..63
    int so = (tid & 3) << 4;    // 0,16,32,48
    int dt  = d >> 4;
    int l15 = d & 15;
    ushortx8 h0, h1;
    #pragma unroll
    for (int j = 0; j < 8; ++j) h0[j] = f32_to_bf16(tile[so + j][d]);
    #pragma unroll
    for (int j = 0; j < 8; ++j) h1[j] = f32_to_bf16(tile[so + 8 + j][d]);
    int sA = s0 + so;          // start s of h0
    int ksA = sA >> 5, qA = (sA & 31) >> 3;
    int sB = sA + 8;           // start s of h1
    int ksB = sB >> 5, qB = (sB & 31) >> 3;
    size_t baseA = ((((size_t)bh * 4 + dt) * 32 + ksA) * 64 + qA * 16 + l15) * 8;
    size_t baseB = ((((size_t)bh * 4 + dt) * 32 + ksB) * 64 + qB * 16 + l15) * 8;
    *(ushortx8*)(vtp + baseA) = h0;
    *(ushortx8*)(vtp + baseB) = h1;
}

// ---- main: per-block = (bh, 16-row q tile); 4 waves ----
__global__ __launch_bounds__(256, 4) void attn_main(
    const float* __restrict__ q,
    const int* __restrict__ mask,
    const unsigned short* __restrict__ KbT,
    const unsigned short* __restrict__ VtP,
    float* __restrict__ out)
{
    __shared__ unsigned short sc[16 * SCN];   // masked scaled scores, bf16
    __shared__ int msk[1024];

    int blk = blockIdx.x;
    int bh = blk >> 6;
    int q0 = (blk & 63) << 4;
    int b  = bh >> 4;
    int tid = threadIdx.x;

    ((intx4*)msk)[tid] = ((const intx4*)(mask + (b << 10)))[tid];

    int w    = tid >> 6;
    int lane = tid & 63;
    int l15  = lane & 15;
    int quad = lane >> 4;

    // Q fragments (A-operand: m=lane&15 (q row), k=quad*8+j (d)); reused all K tiles
    shortx8 qf0, qf1;
    {
        const float* qb = q + ((size_t)(bh * S_ + q0 + l15)) * D_ + quad * 8;
        floatx4 a0 = *(const floatx4*)(qb);
        floatx4 a1 = *(const floatx4*)(qb + 4);
        floatx4 b0 = *(const floatx4*)(qb + 32);
        floatx4 b1 = *(const floatx4*)(qb + 36);
        ushortx8 u0 = pack8u(a0, a1);
        ushortx8 u1 = pack8u(b0, b1);
        qf0 = (shortx8)u0;
        qf1 = (shortx8)u1;
    }

    __syncthreads();

    // ---- Phase 1: S = scale*QK^T, masked, -> LDS bf16 ----
    {
        const unsigned short* kb = KbT + ((size_t)bh * 64 * 64 + lane) * 16;
        for (int kt = w; kt < 64; kt += 4) {
            const unsigned short* p = kb + (size_t)kt * (64 * 16);
            shortx8 kf0 = *(const shortx8*)(p);       // coalesced: lane*32B
            shortx8 kf1 = *(const shortx8*)(p + 8);
            floatx4 acc = {0.f, 0.f, 0.f, 0.f};
            acc = __builtin_amdgcn_mfma_f32_16x16x32_bf16(qf0, kf0, acc, 0, 0, 0);
            acc = __builtin_amdgcn_mfma_f32_16x16x32_bf16(qf1, kf1, acc, 0, 0, 0);
            int n0 = kt << 4;
            int mv = msk[n0 + l15];
            int col = n0 + l15;
            #pragma unroll
            for (int r = 0; r < 4; ++r) {
                // C/D: row(q) = quad*4+r, col(key) = lane&15
                unsigned short h = mv ? f32_to_bf16(acc[r] * 0.125f)
                                      : (unsigned short)0xC61C;  // bf16(-10000) = -9984
                sc[(quad * 4 + r) * SCN + col] = h;
            }
        }
    }
    __syncthreads();

    // ---- Phase 2: row softmax -> attn_weight (fp32, coalesced) ----
    {
        float* attnb = out + ATTN_OFF + ((size_t)(bh * S_ + q0)) * S_;
        for (int rr = 0; rr < 4; ++rr) {
            int row = (w << 2) + rr;
            const unsigned short* srow = sc + row * SCN;
            float vv[16];
            #pragma unroll
            for (int c = 0; c < 2; ++c) {
                ushortx8 h = *(const ushortx8*)(srow + (c << 9) + lane * 8);
                #pragma unroll
                for (int j = 0; j < 8; ++j) vv[c * 8 + j] = bf16_to_f32(h[j]);
            }
            float m = vv[0];
            #pragma unroll
            for (int j = 1; j < 16; ++j) m = fmaxf(m, vv[j]);
            #pragma unroll
            for (int off = 32; off; off >>= 1) m = fmaxf(m, __shfl_xor(m, off));
            float s = 0.f;
            #pragma unroll
            for (int j = 0; j < 16; ++j) { vv[j] = __expf(vv[j] - m); s += vv[j]; }
            #pragma unroll
            for (int off = 32; off; off >>= 1) s += __shfl_xor(s, off);
            float inv = 1.0f / s;
            float* arow = attnb + (size_t)row * S_ + lane * 8;
            #pragma unroll
            for (int c = 0; c < 2; ++c) {
                floatx4 o0 = { vv[c*8+0]*inv, vv[c*8+1]*inv, vv[c*8+2]*inv, vv[c*8+3]*inv };
                floatx4 o1 = { vv[c*8+4]*inv, vv[c*8+5]*inv, vv[c*8+6]*inv, vv[c*8+7]*inv };
                *(floatx4*)(arow + (c << 9))     = o0;
                *(floatx4*)(arow + (c << 9) + 4) = o1;
            }
        }
    }

    // ---- Phase 3: O = S_masked @ V (bug-faithful) ----
    {
        const unsigned short* vb = VtP + (((size_t)bh * 4 + w) * 32) * (64 * 8) + lane * 8;
        const unsigned short* sr = sc + l15 * SCN + quad * 8;
        floatx4 oacc = {0.f, 0.f, 0.f, 0.f};
        #pragma unroll 4
        for (int ks = 0; ks < 32; ++ks) {
            shortx8 af = *(const shortx8*)(sr + (ks << 5));        // LDS
            shortx8 bf = *(const shortx8*)(vb + (ks << 9));        // coalesced: lane*16B
            oacc = __builtin_amdgcn_mfma_f32_16x16x32_bf16(af, bf, oacc, 0, 0, 0);
        }
        int d0 = w << 4;
        float* ob = out + ((size_t)(bh * S_ + q0 + (quad << 2))) * D_ + d0 + l15;
        #pragma unroll
        for (int r = 0; r < 4; ++r) ob[(size_t)r * D_] = oacc[r];
    }
}

extern "C" void kernel_launch(void* const* d_in, const int* in_sizes, int n_in,
                              void* d_out, int out_size, void* d_ws, size_t ws_size,
                              hipStream_t stream) {
    const float* q   = (const float*)d_in[0];
    const float* k   = (const float*)d_in[1];
    const float* v   = (const float*)d_in[2];
    const int* mask  = (const int*)d_in[3];
    float* out = (float*)d_out;
    unsigned short* KbT = (unsigned short*)d_ws;       // 8 MB
    unsigned short* VtP = KbT + NELEM_;                // 8 MB
    kpack<<<1024, 256, 0, stream>>>(k, KbT);
    vpack<<<1024, 256, 0, stream>>>(v, VtP);
    attn_main<<<4096, 256, 0, stream>>>(q, mask, KbT, VtP, out);
}

// Round 3
// 378.273 us; speedup vs baseline: 1.1212x; 1.0046x over previous
//
#include <hip/hip_runtime.h>

// SDPAttention (bug-faithful: output = masked_scores @ v, NOT softmax @ v)
// B=4 H=16 S=1024 DK=64, fp32 in/out.
// R3: XCD-locality swizzle in attn_main. Each XCD (blk&7, round-robin
// heuristic) owns 8 heads, walked sequentially -> resident blocks per XCD
// share ~1-2 heads (512KB K+V) -> KbT/VtP re-reads (1 GB logical) become
// per-XCD L2 hits instead of L3/HBM streams. Also merged pack kernels.
// d_ws: [0,8MB) KbT[bh][kt][lane][16]; [8MB,16MB) VtP[bh][dt][ks][lane][8]

typedef __attribute__((ext_vector_type(4))) float floatx4;
typedef __attribute__((ext_vector_type(8))) short shortx8;
typedef __attribute__((ext_vector_type(8))) unsigned short ushortx8;
typedef __attribute__((ext_vector_type(4))) int intx4;

#define S_ 1024
#define D_ 64
#define NELEM_ 4194304      // B*H*S*DK
#define ATTN_OFF 4194304    // output elements before attn_weight
#define SCN 1040            // LDS score row stride (ushorts); 2080B rows, 16B aligned

__device__ __forceinline__ unsigned short f32_to_bf16(float f) {
    union { float f; unsigned u; } a; a.f = f;
    unsigned u = a.u;
    u += 0x7fffu + ((u >> 16) & 1u);   // round-to-nearest-even
    return (unsigned short)(u >> 16);
}

__device__ __forceinline__ float bf16_to_f32(unsigned short h) {
    union { unsigned u; float f; } a; a.u = ((unsigned)h) << 16;
    return a.f;
}

__device__ __forceinline__ ushortx8 pack8u(floatx4 a, floatx4 b) {
    ushortx8 r;
    r[0] = f32_to_bf16(a[0]); r[1] = f32_to_bf16(a[1]);
    r[2] = f32_to_bf16(a[2]); r[3] = f32_to_bf16(a[3]);
    r[4] = f32_to_bf16(b[0]); r[5] = f32_to_bf16(b[1]);
    r[6] = f32_to_bf16(b[2]); r[7] = f32_to_bf16(b[3]);
    return r;
}

// ---- merged pre-kernel: blocks [0,1024) pack K, [1024,2048) pack V ----
__global__ __launch_bounds__(256) void pack_kv(const float* __restrict__ k,
                                               const float* __restrict__ v,
                                               unsigned short* __restrict__ kbt,
                                               unsigned short* __restrict__ vtp) {
    __shared__ float tile[64][65];
    if (blockIdx.x < 1024) {
        // K fp32 [bh][s][d] -> KbT fragment-major bf16
        int g = blockIdx.x * 256 + threadIdx.x;   // 262144 total
        int lane = g & 63;
        int kt   = (g >> 6) & 63;
        int bh   = g >> 12;
        int quad = lane >> 4;
        int l15  = lane & 15;
        const float* src = k + ((size_t)(bh * S_ + kt * 16 + l15)) * D_ + quad * 8;
        floatx4 f0 = *(const floatx4*)(src);
        floatx4 f1 = *(const floatx4*)(src + 4);
        floatx4 f2 = *(const floatx4*)(src + 32);
        floatx4 f3 = *(const floatx4*)(src + 36);
        unsigned short* dst = kbt + (size_t)g * 16;
        *(ushortx8*)(dst)     = pack8u(f0, f1);
        *(ushortx8*)(dst + 8) = pack8u(f2, f3);
    } else {
        // V fp32 [bh][s][d] -> VtP fragment-major bf16 via LDS transpose
        int blk = blockIdx.x - 1024;
        int bh = blk >> 4;
        int s0 = (blk & 15) << 6;
        int tid = threadIdx.x;
        int r  = tid >> 2;
        int c0 = (tid & 3) << 4;
        const float* src = v + ((size_t)(bh * S_ + s0 + r)) * D_ + c0;
        #pragma unroll
        for (int j = 0; j < 4; ++j) {
            floatx4 f = *(const floatx4*)(src + j * 4);
            tile[r][c0 + j*4 + 0] = f[0];
            tile[r][c0 + j*4 + 1] = f[1];
            tile[r][c0 + j*4 + 2] = f[2];
            tile[r][c0 + j*4 + 3] = f[3];
        }
        __syncthreads();
        int d  = tid >> 2;          // 0..63
        int so = (tid & 3) << 4;    // 0,16,32,48
        int dt  = d >> 4;
        int l15 = d & 15;
        ushortx8 h0, h1;
        #pragma unroll
        for (int j = 0; j < 8; ++j) h0[j] = f32_to_bf16(tile[so + j][d]);
        #pragma unroll
        for (int j = 0; j < 8; ++j) h1[j] = f32_to_bf16(tile[so + 8 + j][d]);
        int sA = s0 + so;
        int ksA = sA >> 5, qA = (sA & 31) >> 3;
        int sB = sA + 8;
        int ksB = sB >> 5, qB = (sB & 31) >> 3;
        size_t baseA = ((((size_t)bh * 4 + dt) * 32 + ksA) * 64 + qA * 16 + l15) * 8;
        size_t baseB = ((((size_t)bh * 4 + dt) * 32 + ksB) * 64 + qB * 16 + l15) * 8;
        *(ushortx8*)(vtp + baseA) = h0;
        *(ushortx8*)(vtp + baseB) = h1;
    }
}

// ---- main: per-block = (bh, 16-row q tile); 4 waves; XCD-locality swizzle ----
__global__ __launch_bounds__(256, 4) void attn_main(
    const float* __restrict__ q,
    const int* __restrict__ mask,
    const unsigned short* __restrict__ KbT,
    const unsigned short* __restrict__ VtP,
    float* __restrict__ out)
{
    __shared__ unsigned short sc[16 * SCN];   // masked scaled scores, bf16
    __shared__ int msk[1024];

    // XCD-aware remap: xcd = blk&7 (round-robin heuristic). Each XCD owns 8
    // heads, walks them sequentially -> resident K/V working set per XCD
    // ~1-2 heads (~512KB) -> L2-resident re-reads.
    int g   = blockIdx.x;
    int xcd = g & 7;
    int i   = g >> 3;                 // 0..511 within this XCD
    int bh  = xcd * 8 + (i >> 6);     // 8 heads per XCD
    int q0  = (i & 63) << 4;
    int b   = bh >> 4;
    int tid = threadIdx.x;

    ((intx4*)msk)[tid] = ((const intx4*)(mask + (b << 10)))[tid];

    int w    = tid >> 6;
    int lane = tid & 63;
    int l15  = lane & 15;
    int quad = lane >> 4;

    // Q fragments (A-operand: m=lane&15 (q row), k=quad*8+j (d))
    shortx8 qf0, qf1;
    {
        const float* qb = q + ((size_t)(bh * S_ + q0 + l15)) * D_ + quad * 8;
        floatx4 a0 = *(const floatx4*)(qb);
        floatx4 a1 = *(const floatx4*)(qb + 4);
        floatx4 b0 = *(const floatx4*)(qb + 32);
        floatx4 b1 = *(const floatx4*)(qb + 36);
        ushortx8 u0 = pack8u(a0, a1);
        ushortx8 u1 = pack8u(b0, b1);
        qf0 = (shortx8)u0;
        qf1 = (shortx8)u1;
    }

    __syncthreads();

    // ---- Phase 1: S = scale*QK^T, masked, -> LDS bf16 ----
    {
        const unsigned short* kb = KbT + ((size_t)bh * 64 * 64 + lane) * 16;
        for (int kt = w; kt < 64; kt += 4) {
            const unsigned short* p = kb + (size_t)kt * (64 * 16);
            shortx8 kf0 = *(const shortx8*)(p);       // coalesced: lane*32B
            shortx8 kf1 = *(const shortx8*)(p + 8);
            floatx4 acc = {0.f, 0.f, 0.f, 0.f};
            acc = __builtin_amdgcn_mfma_f32_16x16x32_bf16(qf0, kf0, acc, 0, 0, 0);
            acc = __builtin_amdgcn_mfma_f32_16x16x32_bf16(qf1, kf1, acc, 0, 0, 0);
            int n0 = kt << 4;
            int mv = msk[n0 + l15];
            int col = n0 + l15;
            #pragma unroll
            for (int r = 0; r < 4; ++r) {
                // C/D: row(q) = quad*4+r, col(key) = lane&15
                unsigned short h = mv ? f32_to_bf16(acc[r] * 0.125f)
                                      : (unsigned short)0xC61C;  // bf16(-10000) = -9984
                sc[(quad * 4 + r) * SCN + col] = h;
            }
        }
    }
    __syncthreads();

    // ---- Phase 2: row softmax -> attn_weight (fp32, coalesced) ----
    {
        float* attnb = out + ATTN_OFF + ((size_t)(bh * S_ + q0)) * S_;
        for (int rr = 0; rr < 4; ++rr) {
            int row = (w << 2) + rr;
            const unsigned short* srow = sc + row * SCN;
            float vv[16];
            #pragma unroll
            for (int c = 0; c < 2; ++c) {
                ushortx8 h = *(const ushortx8*)(srow + (c << 9) + lane * 8);
                #pragma unroll
                for (int j = 0; j < 8; ++j) vv[c * 8 + j] = bf16_to_f32(h[j]);
            }
            float m = vv[0];
            #pragma unroll
            for (int j = 1; j < 16; ++j) m = fmaxf(m, vv[j]);
            #pragma unroll
            for (int off = 32; off; off >>= 1) m = fmaxf(m, __shfl_xor(m, off));
            float s = 0.f;
            #pragma unroll
            for (int j = 0; j < 16; ++j) { vv[j] = __expf(vv[j] - m); s += vv[j]; }
            #pragma unroll
            for (int off = 32; off; off >>= 1) s += __shfl_xor(s, off);
            float inv = 1.0f / s;
            float* arow = attnb + (size_t)row * S_ + lane * 8;
            #pragma unroll
            for (int c = 0; c < 2; ++c) {
                floatx4 o0 = { vv[c*8+0]*inv, vv[c*8+1]*inv, vv[c*8+2]*inv, vv[c*8+3]*inv };
                floatx4 o1 = { vv[c*8+4]*inv, vv[c*8+5]*inv, vv[c*8+6]*inv, vv[c*8+7]*inv };
                *(floatx4*)(arow + (c << 9))     = o0;
                *(floatx4*)(arow + (c << 9) + 4) = o1;
            }
        }
    }

    // ---- Phase 3: O = S_masked @ V (bug-faithful) ----
    {
        const unsigned short* vb = VtP + (((size_t)bh * 4 + w) * 32) * (64 * 8) + lane * 8;
        const unsigned short* sr = sc + l15 * SCN + quad * 8;
        floatx4 oacc = {0.f, 0.f, 0.f, 0.f};
        #pragma unroll 4
        for (int ks = 0; ks < 32; ++ks) {
            shortx8 af = *(const shortx8*)(sr + (ks << 5));        // LDS
            shortx8 bf = *(const shortx8*)(vb + (ks << 9));        // coalesced: lane*16B
            oacc = __builtin_amdgcn_mfma_f32_16x16x32_bf16(af, bf, oacc, 0, 0, 0);
        }
        int d0 = w << 4;
        float* ob = out + ((size_t)(bh * S_ + q0 + (quad << 2))) * D_ + d0 + l15;
        #pragma unroll
        for (int r = 0; r < 4; ++r) ob[(size_t)r * D_] = oacc[r];
    }
}

extern "C" void kernel_launch(void* const* d_in, const int* in_sizes, int n_in,
                              void* d_out, int out_size, void* d_ws, size_t ws_size,
                              hipStream_t stream) {
    const float* q   = (const float*)d_in[0];
    const float* k   = (const float*)d_in[1];
    const float* v   = (const float*)d_in[2];
    const int* mask  = (const int*)d_in[3];
    float* out = (float*)d_out;
    unsigned short* KbT = (unsigned short*)d_ws;       // 8 MB
    unsigned short* VtP = KbT + NELEM_;                // 8 MB
    pack_kv<<<2048, 256, 0, stream>>>(k, v, KbT, VtP);
    attn_main<<<4096, 256, 0, stream>>>(q, mask, KbT, VtP, out);
}

// Round 4
// 369.841 us; speedup vs baseline: 1.1468x; 1.0228x over previous
//
#include <hip/hip_runtime.h>

// SDPAttention (bug-faithful: output = masked_scores @ v, NOT softmax @ v)
// B=4 H=16 S=1024 DK=64, fp32 in/out.
// R4: Qtile 16->64 (1024-thr blocks, 16 waves, 133KB LDS score tile).
// Per-block K/V re-read factor drops S/Qtile = 64 -> 16: 1 GB -> 256 MB of
// L3 traffic. Waves = 4 row-groups x 4 col-groups; phase2 (softmax+write)
// and phase3 (Sc@V MFMA) are independent (reference bug) -> staggered by
// wave parity to overlap write stream with MFMA/read stream.
// d_ws: [0,8MB) KbT[bh][kt][lane][16]; [8MB,16MB) VtP[bh][dt][ks][lane][8]

typedef __attribute__((ext_vector_type(4))) float floatx4;
typedef __attribute__((ext_vector_type(8))) short shortx8;
typedef __attribute__((ext_vector_type(8))) unsigned short ushortx8;
typedef __attribute__((ext_vector_type(4))) int intx4;

#define S_ 1024
#define D_ 64
#define NELEM_ 4194304      // B*H*S*DK
#define ATTN_OFF 4194304    // output elements before attn_weight
#define SCN 1040            // LDS score row stride (ushorts); 2080B rows, 16B aligned

__device__ __forceinline__ unsigned short f32_to_bf16(float f) {
    union { float f; unsigned u; } a; a.f = f;
    unsigned u = a.u;
    u += 0x7fffu + ((u >> 16) & 1u);   // round-to-nearest-even
    return (unsigned short)(u >> 16);
}

__device__ __forceinline__ float bf16_to_f32(unsigned short h) {
    union { unsigned u; float f; } a; a.u = ((unsigned)h) << 16;
    return a.f;
}

__device__ __forceinline__ ushortx8 pack8u(floatx4 a, floatx4 b) {
    ushortx8 r;
    r[0] = f32_to_bf16(a[0]); r[1] = f32_to_bf16(a[1]);
    r[2] = f32_to_bf16(a[2]); r[3] = f32_to_bf16(a[3]);
    r[4] = f32_to_bf16(b[0]); r[5] = f32_to_bf16(b[1]);
    r[6] = f32_to_bf16(b[2]); r[7] = f32_to_bf16(b[3]);
    return r;
}

// ---- merged pre-kernel: blocks [0,1024) pack K, [1024,2048) pack V ----
__global__ __launch_bounds__(256) void pack_kv(const float* __restrict__ k,
                                               const float* __restrict__ v,
                                               unsigned short* __restrict__ kbt,
                                               unsigned short* __restrict__ vtp) {
    __shared__ float tile[64][65];
    if (blockIdx.x < 1024) {
        // K fp32 [bh][s][d] -> KbT fragment-major bf16
        int g = blockIdx.x * 256 + threadIdx.x;   // 262144 total
        int lane = g & 63;
        int kt   = (g >> 6) & 63;
        int bh   = g >> 12;
        int quad = lane >> 4;
        int l15  = lane & 15;
        const float* src = k + ((size_t)(bh * S_ + kt * 16 + l15)) * D_ + quad * 8;
        floatx4 f0 = *(const floatx4*)(src);
        floatx4 f1 = *(const floatx4*)(src + 4);
        floatx4 f2 = *(const floatx4*)(src + 32);
        floatx4 f3 = *(const floatx4*)(src + 36);
        unsigned short* dst = kbt + (size_t)g * 16;
        *(ushortx8*)(dst)     = pack8u(f0, f1);
        *(ushortx8*)(dst + 8) = pack8u(f2, f3);
    } else {
        // V fp32 [bh][s][d] -> VtP fragment-major bf16 via LDS transpose
        int blk = blockIdx.x - 1024;
        int bh = blk >> 4;
        int s0 = (blk & 15) << 6;
        int tid = threadIdx.x;
        int r  = tid >> 2;
        int c0 = (tid & 3) << 4;
        const float* src = v + ((size_t)(bh * S_ + s0 + r)) * D_ + c0;
        #pragma unroll
        for (int j = 0; j < 4; ++j) {
            floatx4 f = *(const floatx4*)(src + j * 4);
            tile[r][c0 + j*4 + 0] = f[0];
            tile[r][c0 + j*4 + 1] = f[1];
            tile[r][c0 + j*4 + 2] = f[2];
            tile[r][c0 + j*4 + 3] = f[3];
        }
        __syncthreads();
        int d  = tid >> 2;          // 0..63
        int so = (tid & 3) << 4;    // 0,16,32,48
        int dt  = d >> 4;
        int l15 = d & 15;
        ushortx8 h0, h1;
        #pragma unroll
        for (int j = 0; j < 8; ++j) h0[j] = f32_to_bf16(tile[so + j][d]);
        #pragma unroll
        for (int j = 0; j < 8; ++j) h1[j] = f32_to_bf16(tile[so + 8 + j][d]);
        int sA = s0 + so;
        int ksA = sA >> 5, qA = (sA & 31) >> 3;
        int sB = sA + 8;
        int ksB = sB >> 5, qB = (sB & 31) >> 3;
        size_t baseA = ((((size_t)bh * 4 + dt) * 32 + ksA) * 64 + qA * 16 + l15) * 8;
        size_t baseB = ((((size_t)bh * 4 + dt) * 32 + ksB) * 64 + qB * 16 + l15) * 8;
        *(ushortx8*)(vtp + baseA) = h0;
        *(ushortx8*)(vtp + baseB) = h1;
    }
}

// ---- main: per-block = (bh, 64-row q tile); 16 waves = 4 rg x 4 cg ----
__global__ __launch_bounds__(1024, 4) void attn_main(
    const float* __restrict__ q,
    const int* __restrict__ mask,
    const unsigned short* __restrict__ KbT,
    const unsigned short* __restrict__ VtP,
    float* __restrict__ out)
{
    __shared__ unsigned short sc[64 * SCN];   // 133,120 B masked scaled scores (bf16)
    __shared__ int msk[1024];

    int blk = blockIdx.x;             // 1024 blocks
    int bh  = blk >> 4;
    int q0  = (blk & 15) << 6;
    int b   = bh >> 4;
    int tid = threadIdx.x;

    msk[tid] = mask[(b << 10) + tid];

    int w    = tid >> 6;              // 0..15
    int lane = tid & 63;
    int l15  = lane & 15;
    int quad = lane >> 4;
    int rg   = w & 3;                 // row-group: q rows [rg*16, rg*16+16)
    int cg   = w >> 2;                // col-group: kt in [cg*16, cg*16+16) / d-tile cg

    // Q fragments (A: m=lane&15 (q row within tile), k=quad*8+j (d))
    shortx8 qf0, qf1;
    {
        const float* qb = q + ((size_t)(bh * S_ + q0 + rg * 16 + l15)) * D_ + quad * 8;
        floatx4 a0 = *(const floatx4*)(qb);
        floatx4 a1 = *(const floatx4*)(qb + 4);
        floatx4 b0 = *(const floatx4*)(qb + 32);
        floatx4 b1 = *(const floatx4*)(qb + 36);
        ushortx8 u0 = pack8u(a0, a1);
        ushortx8 u1 = pack8u(b0, b1);
        qf0 = (shortx8)u0;
        qf1 = (shortx8)u1;
    }

    __syncthreads();

    // ---- Phase 1: Sc = scale*QK^T, masked, -> LDS bf16 ----
    {
        const unsigned short* kb = KbT + ((size_t)bh * 64 * 64 + lane) * 16;
        #pragma unroll 4
        for (int t = 0; t < 16; ++t) {
            int kt = (cg << 4) + t;
            const unsigned short* p = kb + (size_t)kt * (64 * 16);
            shortx8 kf0 = *(const shortx8*)(p);       // coalesced: lane*32B
            shortx8 kf1 = *(const shortx8*)(p + 8);
            floatx4 acc = {0.f, 0.f, 0.f, 0.f};
            acc = __builtin_amdgcn_mfma_f32_16x16x32_bf16(qf0, kf0, acc, 0, 0, 0);
            acc = __builtin_amdgcn_mfma_f32_16x16x32_bf16(qf1, kf1, acc, 0, 0, 0);
            int n0 = kt << 4;
            int mv = msk[n0 + l15];
            int col = n0 + l15;
            #pragma unroll
            for (int r = 0; r < 4; ++r) {
                // C/D: row(q within 16-tile) = quad*4+r, col(key) = lane&15
                unsigned short h = mv ? f32_to_bf16(acc[r] * 0.125f)
                                      : (unsigned short)0xC61C;  // bf16(-10000) = -9984
                sc[(rg * 16 + quad * 4 + r) * SCN + col] = h;
            }
        }
    }
    __syncthreads();

    // ---- Phase 2: row softmax -> attn_weight; Phase 3: O = Sc @ V ----
    // Independent (reference bug: O uses raw masked scores). Stagger by wave
    // parity so HBM-write burst (P2) overlaps MFMA/read burst (P3).
    auto phase2 = [&]() {
        float* attnb = out + ATTN_OFF + ((size_t)(bh * S_ + q0)) * S_;
        for (int rr = 0; rr < 4; ++rr) {
            int row = (w << 2) + rr;                 // w=0..15 -> rows 0..63
            const unsigned short* srow = sc + row * SCN;
            float vv[16];
            #pragma unroll
            for (int c = 0; c < 2; ++c) {
                ushortx8 h = *(const ushortx8*)(srow + (c << 9) + lane * 8);
                #pragma unroll
                for (int j = 0; j < 8; ++j) vv[c * 8 + j] = bf16_to_f32(h[j]);
            }
            float m = vv[0];
            #pragma unroll
            for (int j = 1; j < 16; ++j) m = fmaxf(m, vv[j]);
            #pragma unroll
            for (int off = 32; off; off >>= 1) m = fmaxf(m, __shfl_xor(m, off));
            float s = 0.f;
            #pragma unroll
            for (int j = 0; j < 16; ++j) { vv[j] = __expf(vv[j] - m); s += vv[j]; }
            #pragma unroll
            for (int off = 32; off; off >>= 1) s += __shfl_xor(s, off);
            float inv = 1.0f / s;
            float* arow = attnb + (size_t)row * S_ + lane * 8;
            #pragma unroll
            for (int c = 0; c < 2; ++c) {
                floatx4 o0 = { vv[c*8+0]*inv, vv[c*8+1]*inv, vv[c*8+2]*inv, vv[c*8+3]*inv };
                floatx4 o1 = { vv[c*8+4]*inv, vv[c*8+5]*inv, vv[c*8+6]*inv, vv[c*8+7]*inv };
                *(floatx4*)(arow + (c << 9))     = o0;
                *(floatx4*)(arow + (c << 9) + 4) = o1;
            }
        }
    };
    auto phase3 = [&]() {
        // wave (rg,cg): O tile rows [rg*16..), d cols [cg*16..)
        const unsigned short* vb = VtP + (((size_t)bh * 4 + cg) * 32) * (64 * 8) + lane * 8;
        const unsigned short* sr = sc + (rg * 16 + l15) * SCN + quad * 8;
        floatx4 oacc = {0.f, 0.f, 0.f, 0.f};
        #pragma unroll 4
        for (int ks = 0; ks < 32; ++ks) {
            shortx8 af = *(const shortx8*)(sr + (ks << 5));        // LDS A-frag
            shortx8 bf = *(const shortx8*)(vb + (ks << 9));        // coalesced 16B/lane
            oacc = __builtin_amdgcn_mfma_f32_16x16x32_bf16(af, bf, oacc, 0, 0, 0);
        }
        float* ob = out + ((size_t)(bh * S_ + q0 + rg * 16 + (quad << 2))) * D_
                        + (cg << 4) + l15;
        #pragma unroll
        for (int r = 0; r < 4; ++r) ob[(size_t)r * D_] = oacc[r];
    };
    if (w & 1) { phase3(); phase2(); }
    else       { phase2(); phase3(); }
}

extern "C" void kernel_launch(void* const* d_in, const int* in_sizes, int n_in,
                              void* d_out, int out_size, void* d_ws, size_t ws_size,
                              hipStream_t stream) {
    const float* q   = (const float*)d_in[0];
    const float* k   = (const float*)d_in[1];
    const float* v   = (const float*)d_in[2];
    const int* mask  = (const int*)d_in[3];
    float* out = (float*)d_out;
    unsigned short* KbT = (unsigned short*)d_ws;       // 8 MB
    unsigned short* VtP = KbT + NELEM_;                // 8 MB
    pack_kv<<<2048, 256, 0, stream>>>(k, v, KbT, VtP);
    attn_main<<<1024, 1024, 0, stream>>>(q, mask, KbT, VtP, out);
}